// Round 2
// baseline (385.213 us; speedup 1.0000x reference)
//
#include <hip/hip_runtime.h>

#define NROWS (32 * 64 * 64)   // 131072 rows (b,h,w)
#define CDIM 64
#define KCODES 1024
#define ZQ_ELEMS (32 * 64 * 64 * 64)  // 8388608
#define FLT_BIG 3.402823466e38f

// Replicate numpy float32 semantics:
//   A_n = pairwise64(z_c^2)  (numpy 8-accumulator pairwise sum)
//   B_k = pairwise64(e_c^2)
//   M_nk = sequential fma over c (BLAS sgemm microkernel order)
//   d = fl(fl(A+B_k) - 2*M_nk) ; argmin, first index wins (strict <)
__global__ __launch_bounds__(256) void vq_main(const float* __restrict__ z,
                                               const float* __restrict__ cb,
                                               float* __restrict__ zq_out,
                                               float* __restrict__ idx_out,
                                               double* __restrict__ part) {
    __shared__ float sB[KCODES];
    __shared__ double sWave[4];
    const int tid = threadIdx.x;

    // B_k with numpy pairwise semantics
    for (int k = tid; k < KCODES; k += 256) {
        const float* ck = cb + k * CDIM;
        float r[8];
        #pragma unroll
        for (int j = 0; j < 8; ++j) r[j] = __fmul_rn(ck[j], ck[j]);
        #pragma unroll
        for (int m = 1; m < 8; ++m) {
            #pragma unroll
            for (int j = 0; j < 8; ++j)
                r[j] = __fadd_rn(r[j], __fmul_rn(ck[8 * m + j], ck[8 * m + j]));
        }
        sB[k] = __fadd_rn(__fadd_rn(__fadd_rn(r[0], r[1]), __fadd_rn(r[2], r[3])),
                          __fadd_rn(__fadd_rn(r[4], r[5]), __fadd_rn(r[6], r[7])));
    }
    __syncthreads();

    const int n = blockIdx.x * 256 + tid;       // row id
    const int b = n >> 12;
    const int hw = n & 4095;
    const float* zp = z + ((size_t)b << 18) + hw;

    float zv[CDIM];
    #pragma unroll
    for (int c = 0; c < CDIM; ++c) zv[c] = zp[c << 12];

    // A with numpy pairwise semantics
    float A;
    {
        float r[8];
        #pragma unroll
        for (int j = 0; j < 8; ++j) r[j] = __fmul_rn(zv[j], zv[j]);
        #pragma unroll
        for (int m = 1; m < 8; ++m) {
            #pragma unroll
            for (int j = 0; j < 8; ++j)
                r[j] = __fadd_rn(r[j], __fmul_rn(zv[8 * m + j], zv[8 * m + j]));
        }
        A = __fadd_rn(__fadd_rn(__fadd_rn(r[0], r[1]), __fadd_rn(r[2], r[3])),
                      __fadd_rn(__fadd_rn(r[4], r[5]), __fadd_rn(r[6], r[7])));
    }

    float best = FLT_BIG;
    int bi = 0;

    for (int k = 0; k < KCODES; k += 4) {
        const float4* C0 = (const float4*)(cb + (size_t)(k + 0) * CDIM);
        const float4* C1 = (const float4*)(cb + (size_t)(k + 1) * CDIM);
        const float4* C2 = (const float4*)(cb + (size_t)(k + 2) * CDIM);
        const float4* C3 = (const float4*)(cb + (size_t)(k + 3) * CDIM);
        float m0 = 0.f, m1 = 0.f, m2 = 0.f, m3 = 0.f;
        #pragma unroll
        for (int q = 0; q < CDIM / 4; ++q) {
            float4 e0 = C0[q], e1 = C1[q], e2 = C2[q], e3 = C3[q];
            float z0 = zv[4 * q + 0], z1 = zv[4 * q + 1], z2 = zv[4 * q + 2], z3 = zv[4 * q + 3];
            // strictly sequential in c for each accumulator (sgemm order)
            m0 = __fmaf_rn(z0, e0.x, m0);
            m0 = __fmaf_rn(z1, e0.y, m0);
            m0 = __fmaf_rn(z2, e0.z, m0);
            m0 = __fmaf_rn(z3, e0.w, m0);
            m1 = __fmaf_rn(z0, e1.x, m1);
            m1 = __fmaf_rn(z1, e1.y, m1);
            m1 = __fmaf_rn(z2, e1.z, m1);
            m1 = __fmaf_rn(z3, e1.w, m1);
            m2 = __fmaf_rn(z0, e2.x, m2);
            m2 = __fmaf_rn(z1, e2.y, m2);
            m2 = __fmaf_rn(z2, e2.z, m2);
            m2 = __fmaf_rn(z3, e2.w, m2);
            m3 = __fmaf_rn(z0, e3.x, m3);
            m3 = __fmaf_rn(z1, e3.y, m3);
            m3 = __fmaf_rn(z2, e3.z, m3);
            m3 = __fmaf_rn(z3, e3.w, m3);
        }
        // d = (A + B_k) - 2*M, compare in ascending k (first-index tie-break via strict <)
        float d0 = __fsub_rn(__fadd_rn(A, sB[k + 0]), __fadd_rn(m0, m0));
        float d1 = __fsub_rn(__fadd_rn(A, sB[k + 1]), __fadd_rn(m1, m1));
        float d2 = __fsub_rn(__fadd_rn(A, sB[k + 2]), __fadd_rn(m2, m2));
        float d3 = __fsub_rn(__fadd_rn(A, sB[k + 3]), __fadd_rn(m3, m3));
        if (d0 < best) { best = d0; bi = k + 0; }
        if (d1 < best) { best = d1; bi = k + 1; }
        if (d2 < best) { best = d2; bi = k + 2; }
        if (d3 < best) { best = d3; bi = k + 3; }
    }

    idx_out[n] = (float)bi;

    // z_q write + loss partial
    const float4* cq4 = (const float4*)(cb + (size_t)bi * CDIM);
    float* zo = zq_out + ((size_t)b << 18) + hw;
    float lsum = 0.f;
    #pragma unroll
    for (int c4 = 0; c4 < CDIM / 4; ++c4) {
        float4 q = cq4[c4];
        zo[(4 * c4 + 0) << 12] = q.x;
        zo[(4 * c4 + 1) << 12] = q.y;
        zo[(4 * c4 + 2) << 12] = q.z;
        zo[(4 * c4 + 3) << 12] = q.w;
        float d0 = q.x - zv[4 * c4 + 0];
        float d1 = q.y - zv[4 * c4 + 1];
        float d2 = q.z - zv[4 * c4 + 2];
        float d3 = q.w - zv[4 * c4 + 3];
        lsum = fmaf(d0, d0, lsum);
        lsum = fmaf(d1, d1, lsum);
        lsum = fmaf(d2, d2, lsum);
        lsum = fmaf(d3, d3, lsum);
    }

    double ls = (double)lsum;
    for (int off = 32; off > 0; off >>= 1) ls += __shfl_down(ls, off, 64);
    if ((tid & 63) == 0) sWave[tid >> 6] = ls;
    __syncthreads();
    if (tid == 0) {
        part[blockIdx.x] = sWave[0] + sWave[1] + sWave[2] + sWave[3];
    }
}

__global__ void vq_finalize(const double* __restrict__ part, float* __restrict__ loss_out) {
    __shared__ double s[8];
    const int tid = threadIdx.x;       // 512 threads, one block
    double v = part[tid];
    for (int off = 32; off > 0; off >>= 1) v += __shfl_down(v, off, 64);
    if ((tid & 63) == 0) s[tid >> 6] = v;
    __syncthreads();
    if (tid == 0) {
        double t = 0.0;
        #pragma unroll
        for (int i = 0; i < 8; ++i) t += s[i];
        // loss = codebook_loss + 0.25*commitment = 1.25 * mean((z_q - z)^2)
        *loss_out = (float)(1.25 * t / (double)ZQ_ELEMS);
    }
}

extern "C" void kernel_launch(void* const* d_in, const int* in_sizes, int n_in,
                              void* d_out, int out_size, void* d_ws, size_t ws_size,
                              hipStream_t stream) {
    const float* z  = (const float*)d_in[0];
    const float* cb = (const float*)d_in[1];
    float* out  = (float*)d_out;
    float* zq   = out;                       // 8388608
    float* loss = out + ZQ_ELEMS;            // 1
    float* idx  = out + ZQ_ELEMS + 1;        // 131072
    double* part = (double*)d_ws;            // 512 doubles

    vq_main<<<512, 256, 0, stream>>>(z, cb, zq, idx, part);
    vq_finalize<<<1, 512, 0, stream>>>(part, loss);
}